// Round 6
// baseline (238.965 us; speedup 1.0000x reference)
//
#include <hip/hip_runtime.h>
#include <hip/hip_bf16.h>

// Head-axis-softmax SDPA, B=2 S=2048 N=16 D=64, fp32 in/out.
// softmax over HEADS (n) -> local per (b,q,k).
//
// R10: q-pair register blocking + bf16 Zr + XCD-resident head planes.
// R9 measured pass2 at ~21 TB/s logical L2 (62% of ceiling) -> traffic-bound.
//   - pass2: 2 q-tiles per block (qf0,qf1 in reg; K/V frags amortized 2x)
//     -> K+V logical reads halve. grid (n, qg, b) so linear%8 = n%8: each
//     head's 512KB K/V plane is L2-RESIDENT per XCD.
//   - Zr stored bf16 (packed fragment layout, cvt_pk in pass1): zr read
//     traffic halves, pass1 HBM writes halve.
//   - pass1: same 2kt x 2qt blocking (16 loads -> 16 MFMA per head iter).
// Both main kernels __launch_bounds__(256,2) (~190 VGPR; ILP replaces occ).

#define B_ 2
#define S_ 2048
#define N_ 16
#define D_ 64
#define TQ 32
#define TK 32
#define NT 64   // S_/32 tiles per head

typedef __bf16 bf16x4 __attribute__((ext_vector_type(4)));
typedef __bf16 bf16x8 __attribute__((ext_vector_type(8)));
typedef float  f32x16 __attribute__((ext_vector_type(16)));
typedef unsigned int uint32x4 __attribute__((ext_vector_type(4)));

// scale folded into Q at conversion: 1/sqrt(64) * log2(e)
#define QSCALE 0.18033688011112042f

static __device__ __forceinline__ unsigned int cvt_pk_bf16(float a, float b) {
    // dst low16 = bf16(a), high16 = bf16(b)
    unsigned int r;
    asm("v_cvt_pk_bf16_f32 %0, %1, %2" : "=v"(r) : "v"(a), "v"(b));
    return r;
}
static __device__ __forceinline__ void permlane_swap(unsigned int& a, unsigned int& b) {
    // exchanges a's lanes[32:63] with b's lanes[0:31]
    asm("v_permlane32_swap_b32 %0, %1" : "+v"(a), "+v"(b));
}

// ---------------------------------------------------------------------------
// Pre-pass 1: Q,K [b,s,n,d] f32 -> fragment-major packed bf16.
// QP,KP[b][n][s-tile][ks][lane][8]; Q pre-scaled by QSCALE.
// ---------------------------------------------------------------------------
__global__ __launch_bounds__(256) void cvt_qk_pack_kernel(
    const float* __restrict__ Qf, const float* __restrict__ Kf,
    __bf16* __restrict__ QP, __bf16* __restrict__ KP)
{
    const int z = blockIdx.z;                  // 0..2B-1: first B -> Q, rest -> K
    const float* src = (z < B_) ? Qf : Kf;
    __bf16*      dst = (z < B_) ? QP : KP;
    const float scale = (z < B_) ? QSCALE : 1.0f;
    const int b  = (z < B_) ? z : z - B_;
    const int n  = blockIdx.y;
    const int st = blockIdx.x;                 // s-tile 0..63
    const int t  = threadIdx.x;
    const int ks   = t >> 6;
    const int lane = t & 63;
    const int lo   = lane & 31;
    const int hi   = lane >> 5;

    const float* p = &src[(((size_t)b * S_ + st * 32 + lo) * N_ + n) * D_ + ks * 16 + hi * 8];
    const float4 a0 = *(const float4*)p;
    const float4 a1 = *(const float4*)(p + 4);
    bf16x8 o;
    o[0] = (__bf16)(a0.x * scale); o[1] = (__bf16)(a0.y * scale);
    o[2] = (__bf16)(a0.z * scale); o[3] = (__bf16)(a0.w * scale);
    o[4] = (__bf16)(a1.x * scale); o[5] = (__bf16)(a1.y * scale);
    o[6] = (__bf16)(a1.z * scale); o[7] = (__bf16)(a1.w * scale);
    *(bf16x8*)&dst[(((size_t)b * N_ + n) * NT + st) * 2048 + (size_t)t * 8] = o;
}

// ---------------------------------------------------------------------------
// Pre-pass 2: V [b,s,n,d] f32 -> fragment-major packed bf16 (via LDS tile).
// VP[b][n][k-tile][kstep][dt][lane][8].
// ---------------------------------------------------------------------------
__global__ __launch_bounds__(256) void cvt_v_pack_kernel(
    const float* __restrict__ V, __bf16* __restrict__ VP)
{
    __shared__ __bf16 tile[64][68];  // +4 pad breaks bank aliasing
    const int s0 = blockIdx.x * 64;
    const int n  = blockIdx.y;
    const int b  = blockIdx.z;
    const int t  = threadIdx.x;

    {
        const int d4 = (t & 15) * 4;
        const int sr = t >> 4;
        #pragma unroll
        for (int r = 0; r < 4; ++r) {
            const int s = sr + r * 16;
            const float4 v = *(const float4*)&V[(((size_t)b * S_ + s0 + s) * N_ + n) * D_ + d4];
            tile[s][d4 + 0] = (__bf16)v.x;
            tile[s][d4 + 1] = (__bf16)v.y;
            tile[s][d4 + 2] = (__bf16)v.z;
            tile[s][d4 + 3] = (__bf16)v.w;
        }
    }
    __syncthreads();
    {
        const int kstep = t >> 7;        // 0..1
        const int dt    = (t >> 6) & 1;
        const int lane  = t & 63;
        const int lo    = lane & 31;
        const int hi    = lane >> 5;
        #pragma unroll
        for (int kt_sub = 0; kt_sub < 2; ++kt_sub) {
            bf16x8 o;
            #pragma unroll
            for (int j = 0; j < 8; ++j)
                o[j] = tile[kt_sub * 32 + kstep * 16 + hi * 8 + j][dt * 32 + lo];
            const size_t kt = (size_t)(blockIdx.x * 2 + kt_sub);
            *(bf16x8*)&VP[(((size_t)b * N_ + n) * NT + kt) * 2048 + (size_t)t * 8] = o;
        }
    }
}

// ---------------------------------------------------------------------------
// Pass 1: Zrb packed bf16 = mask ? 1/sum_n exp2(s_n) : NaN, in pass2's
// fragment layout: Zrb[((b*NT+kt)*NT+qt)*1024 + g*512 + lane*8 + j] holds
// Z^-1 at (q = qt*32+(lane&31), k = kt*32 + kap(g*8+j, lane>>5)),
// kap(r,hi) = (r&3)+8*(r>>2)+4*hi.
// Block = 4 waves; wave wv: k-tiles ktA=(bx*4+wv)*2, ktA+1;
// q-tiles qt0=by*2, qt0+1. SWAPPED QK^T (mfma(K,Q)): C-layout == packed order.
// 2x2 blocking: per head 16 frag loads -> 16 MFMA.
// ---------------------------------------------------------------------------
__global__ __launch_bounds__(256, 2) void pass1_z_kernel(
    const __bf16* __restrict__ QP, const __bf16* __restrict__ KP,
    const int* __restrict__ M, __bf16* __restrict__ Zrb)
{
    const int tid  = threadIdx.x;
    const int wv   = tid >> 6;
    const int lane = tid & 63;
    const int lo   = lane & 31;
    const int hi   = lane >> 5;

    const int ktA = (blockIdx.x * 4 + wv) * 2;
    const int qt0 = blockIdx.y * 2;
    const int b   = blockIdx.z;
    const int k0A = ktA * TK;
    const int q0  = qt0 * TQ;

    const __bf16* Qp = QP + ((size_t)b * N_ * NT + qt0) * 2048 + (size_t)lane * 8;
    const __bf16* Kp = KP + ((size_t)b * N_ * NT + ktA) * 2048 + (size_t)lane * 8;

    f32x16 zAA = {}, zAB = {}, zBA = {}, zBB = {};   // z[kt][qt]
    for (int h = 0; h < N_; ++h) {
        const __bf16* Qh = Qp + (size_t)h * NT * 2048;
        const __bf16* Kh = Kp + (size_t)h * NT * 2048;
        bf16x8 q0f[4], q1f[4], ka[4], kb[4];
        #pragma unroll
        for (int ks = 0; ks < 4; ++ks) {
            q0f[ks] = *(const bf16x8*)(Qh + ks * 512);
            q1f[ks] = *(const bf16x8*)(Qh + 2048 + ks * 512);
            ka[ks]  = *(const bf16x8*)(Kh + ks * 512);
            kb[ks]  = *(const bf16x8*)(Kh + 2048 + ks * 512);
        }
        f32x16 s;
        s = (f32x16){};
        #pragma unroll
        for (int ks = 0; ks < 4; ++ks) s = __builtin_amdgcn_mfma_f32_32x32x16_bf16(ka[ks], q0f[ks], s, 0, 0, 0);
        #pragma unroll
        for (int r = 0; r < 16; ++r) zAA[r] += __builtin_amdgcn_exp2f(s[r]);
        s = (f32x16){};
        #pragma unroll
        for (int ks = 0; ks < 4; ++ks) s = __builtin_amdgcn_mfma_f32_32x32x16_bf16(ka[ks], q1f[ks], s, 0, 0, 0);
        #pragma unroll
        for (int r = 0; r < 16; ++r) zAB[r] += __builtin_amdgcn_exp2f(s[r]);
        s = (f32x16){};
        #pragma unroll
        for (int ks = 0; ks < 4; ++ks) s = __builtin_amdgcn_mfma_f32_32x32x16_bf16(kb[ks], q0f[ks], s, 0, 0, 0);
        #pragma unroll
        for (int r = 0; r < 16; ++r) zBA[r] += __builtin_amdgcn_exp2f(s[r]);
        s = (f32x16){};
        #pragma unroll
        for (int ks = 0; ks < 4; ++ks) s = __builtin_amdgcn_mfma_f32_32x32x16_bf16(kb[ks], q1f[ks], s, 0, 0, 0);
        #pragma unroll
        for (int r = 0; r < 16; ++r) zBB[r] += __builtin_amdgcn_exp2f(s[r]);
    }

    // mask fast-path: AND-reduce rows q0..q0+63 x cols k0A..k0A+63 (int4).
    const size_t mb = (size_t)b * S_ * S_;
    int ok = 1;
    #pragma unroll
    for (int r = 0; r < 16; ++r) {
        const int4 mm = *(const int4*)&M[mb + (size_t)(q0 + 4 * r + (lane >> 4)) * S_
                                         + k0A + (lane & 15) * 4];
        ok &= (mm.x != 0) & (mm.y != 0) & (mm.z != 0) & (mm.w != 0);
    }

    float vAA[16], vAB[16], vBA[16], vBB[16];
    #pragma unroll
    for (int r = 0; r < 16; ++r) {
        vAA[r] = __builtin_amdgcn_rcpf(zAA[r]);
        vAB[r] = __builtin_amdgcn_rcpf(zAB[r]);
        vBA[r] = __builtin_amdgcn_rcpf(zBA[r]);
        vBB[r] = __builtin_amdgcn_rcpf(zBB[r]);
    }

    if (!__all(ok)) {
        // rare slow path: per-element mask (scattered; correctness only).
        // mask==0: ref softmax over all-(-inf) heads -> NaN weights.
        #pragma unroll
        for (int r = 0; r < 16; ++r) {
            const int kap = (r & 3) + 8 * (r >> 2) + 4 * hi;
            const size_t rowA = mb + (size_t)(q0 + lo) * S_;
            const size_t rowB = mb + (size_t)(q0 + 32 + lo) * S_;
            if (M[rowA + k0A + kap] == 0)      vAA[r] = __builtin_nanf("");
            if (M[rowB + k0A + kap] == 0)      vAB[r] = __builtin_nanf("");
            if (M[rowA + k0A + 32 + kap] == 0) vBA[r] = __builtin_nanf("");
            if (M[rowB + k0A + 32 + kap] == 0) vBB[r] = __builtin_nanf("");
        }
    }

    auto store_tile = [&](const float (&v)[16], int kt_, int qt_) {
        __bf16* Zt = Zrb + (((size_t)b * NT + kt_) * NT + qt_) * 1024 + (size_t)lane * 8;
        #pragma unroll
        for (int g = 0; g < 2; ++g) {
            uint32x4 u;
            #pragma unroll
            for (int i = 0; i < 4; ++i)
                u[i] = cvt_pk_bf16(v[g * 8 + 2 * i], v[g * 8 + 2 * i + 1]);
            *(bf16x8*)(Zt + g * 512) = __builtin_bit_cast(bf16x8, u);
        }
    };
    store_tile(vAA, ktA,     qt0);
    store_tile(vAB, ktA,     qt0 + 1);
    store_tile(vBA, ktA + 1, qt0);
    store_tile(vBB, ktA + 1, qt0 + 1);
}

// ---------------------------------------------------------------------------
// Pass 2: out[b,n,q,:] = sum_k (exp2(s)*zr) V[k,:].
// Block = 4 waves, TWO q-tiles (qg) per block; wave w sweeps k-tiles
// [w*16, w*16+16) for both. grid (n, qg, b): linear%8 = n%8 -> each head's
// K/V plane is XCD-L2-resident. Swapped QK^T; cvt_pk+permlane PV A-frags;
// zr = bf16 packed fragment loads. End: per-q-tile LDS combine (32KB obuf).
// ---------------------------------------------------------------------------
__global__ __launch_bounds__(256, 2) void pass2_av_kernel(
    const __bf16* __restrict__ QP, const __bf16* __restrict__ KP,
    const __bf16* __restrict__ VP, const __bf16* __restrict__ Zrb,
    float* __restrict__ O)
{
    __shared__ __align__(16) float obuf[4][TQ * D_];    // 32 KB, end combine

    const int tid  = threadIdx.x;
    const int wv   = tid >> 6;
    const int lane = tid & 63;
    const int lo   = lane & 31;
    const int hi   = lane >> 5;

    const int n   = blockIdx.x;
    const int qt0 = blockIdx.y * 2;
    const int b   = blockIdx.z;

    const __bf16* Qh = QP + (((size_t)b * N_ + n) * NT + qt0) * 2048 + (size_t)lane * 8;
    const __bf16* Kh = KP + (((size_t)b * N_ + n) * NT) * 2048 + (size_t)lane * 8;
    const __bf16* Vh = VP + (((size_t)b * N_ + n) * NT) * 2048 + (size_t)lane * 8;
    const __bf16* Zb = Zrb + (size_t)b * NT * NT * 1024 + (size_t)lane * 8;

    // Q fragments for both q-tiles (pre-scaled). B-operand of swapped QK^T.
    bf16x8 qf0[4], qf1[4];
    #pragma unroll
    for (int ks = 0; ks < 4; ++ks) {
        qf0[ks] = *(const bf16x8*)(Qh + ks * 512);
        qf1[ks] = *(const bf16x8*)(Qh + 2048 + ks * 512);
    }

    f32x16 o00 = {}, o01 = {};   // q-tile 0: cols 0..31 / 32..63
    f32x16 o10 = {}, o11 = {};   // q-tile 1

    for (int t = 0; t < 16; ++t) {
        const int kt = wv * 16 + t;
        const __bf16* Kt = Kh + (size_t)kt * 2048;
        const __bf16* Vt = Vh + (size_t)kt * 2048;
        const __bf16* Zt = Zb + ((size_t)kt * NT + qt0) * 1024;

        // zr (bf16 packed): 4 b128 loads cover BOTH q-tiles.
        const bf16x8 z0a = *(const bf16x8*)(Zt);
        const bf16x8 z0b = *(const bf16x8*)(Zt + 512);
        const bf16x8 z1a = *(const bf16x8*)(Zt + 1024);
        const bf16x8 z1b = *(const bf16x8*)(Zt + 1536);

        // K/V frags: lane-contiguous 1KB each, shared by both q-tiles.
        bf16x8 kf[4];
        #pragma unroll
        for (int ks = 0; ks < 4; ++ks) kf[ks] = *(const bf16x8*)(Kt + ks * 512);
        bf16x8 vf[2][2];
        #pragma unroll
        for (int kstep = 0; kstep < 2; ++kstep)
            #pragma unroll
            for (int dt = 0; dt < 2; ++dt)
                vf[kstep][dt] = *(const bf16x8*)(Vt + (kstep * 2 + dt) * 512);

        // swapped QK^T for both q-tiles (independent chains -> ILP)
        f32x16 s0 = {}, s1 = {};
        #pragma unroll
        for (int ks = 0; ks < 4; ++ks) {
            s0 = __builtin_amdgcn_mfma_f32_32x32x16_bf16(kf[ks], qf0[ks], s0, 0, 0, 0);
            s1 = __builtin_amdgcn_mfma_f32_32x32x16_bf16(kf[ks], qf1[ks], s1, 0, 0, 0);
        }

        // q-tile 0: w = exp2(s)*zr -> pack -> PV
        {
            float w[16];
            #pragma unroll
            for (int r = 0; r < 8; ++r)  w[r] = __builtin_amdgcn_exp2f(s0[r]) * (float)z0a[r];
            #pragma unroll
            for (int r = 8; r < 16; ++r) w[r] = __builtin_amdgcn_exp2f(s0[r]) * (float)z0b[r - 8];
            #pragma unroll
            for (int kstep = 0; kstep < 2; ++kstep) {
                const int e = kstep * 8;
                unsigned int d0 = cvt_pk_bf16(w[e + 0], w[e + 1]);
                unsigned int d1 = cvt_pk_bf16(w[e + 2], w[e + 3]);
                unsigned int d2 = cvt_pk_bf16(w[e + 4], w[e + 5]);
                unsigned int d3 = cvt_pk_bf16(w[e + 6], w[e + 7]);
                permlane_swap(d0, d2);
                permlane_swap(d1, d3);
                uint32x4 u; u[0] = d0; u[1] = d1; u[2] = d2; u[3] = d3;
                const bf16x8 pa = __builtin_bit_cast(bf16x8, u);
                o00 = __builtin_amdgcn_mfma_f32_32x32x16_bf16(pa, vf[kstep][0], o00, 0, 0, 0);
                o01 = __builtin_amdgcn_mfma_f32_32x32x16_bf16(pa, vf[kstep][1], o01, 0, 0, 0);
            }
        }
        // q-tile 1
        {
            float w[16];
            #pragma unroll
            for (int r = 0; r < 8; ++r)  w[r] = __builtin_amdgcn_exp2f(s1[r]) * (float)z1a[r];
            #pragma unroll
            for (int r = 8; r < 16; ++r) w[r] = __builtin_amdgcn_exp2f(s1[r]) * (float)z1b[r - 8];
            #pragma unroll
            for (int kstep = 0; kstep < 2; ++kstep) {
                const int e = kstep * 8;
                unsigned int d0 = cvt_pk_bf16(w[e + 0], w[e + 1]);
                unsigned int d1 = cvt_pk_bf16(w[e + 2], w[e + 3]);
                unsigned int d2 = cvt_pk_bf16(w[e + 4], w[e + 5]);
                unsigned int d3 = cvt_pk_bf16(w[e + 6], w[e + 7]);
                permlane_swap(d0, d2);
                permlane_swap(d1, d3);
                uint32x4 u; u[0] = d0; u[1] = d1; u[2] = d2; u[3] = d3;
                const bf16x8 pa = __builtin_bit_cast(bf16x8, u);
                o10 = __builtin_amdgcn_mfma_f32_32x32x16_bf16(pa, vf[kstep][0], o10, 0, 0, 0);
                o11 = __builtin_amdgcn_mfma_f32_32x32x16_bf16(pa, vf[kstep][1], o11, 0, 0, 0);
            }
        }
    }

    // k-split combine per q-tile: deposit 4 wave-partials, tree-sum, store.
    auto combine_store = [&](const f32x16& a0, const f32x16& a1, int qt_) {
        #pragma unroll
        for (int r = 0; r < 16; ++r) {
            const int row = (r & 3) + 8 * (r >> 2) + 4 * hi;
            obuf[wv][row * D_ + lo]      = a0[r];
            obuf[wv][row * D_ + 32 + lo] = a1[r];
        }
        __syncthreads();
        const int e0 = tid * 8;          // 8 consecutive output f32 per thread
        float b0 = 0.f, b1 = 0.f, b2 = 0.f, b3 = 0.f;
        float b4 = 0.f, b5 = 0.f, b6 = 0.f, b7 = 0.f;
        #pragma unroll
        for (int w = 0; w < 4; ++w) {
            const float4 x = *(const float4*)&obuf[w][e0];
            const float4 y = *(const float4*)&obuf[w][e0 + 4];
            b0 += x.x; b1 += x.y; b2 += x.z; b3 += x.w;
            b4 += y.x; b5 += y.y; b6 += y.z; b7 += y.w;
        }
        const int q = e0 >> 6;
        const int d = e0 & 63;
        float* dst = &O[(((size_t)b * N_ + n) * S_ + qt_ * TQ + q) * (size_t)D_ + d];
        *(float4*)dst       = make_float4(b0, b1, b2, b3);
        *(float4*)(dst + 4) = make_float4(b4, b5, b6, b7);
    };
    combine_store(o00, o01, qt0);
    __syncthreads();
    combine_store(o10, o11, qt0 + 1);
}

// ---------------------------------------------------------------------------
// Fallback (fp32 inputs): used only if ws is too small.
// ---------------------------------------------------------------------------
__global__ __launch_bounds__(1024) void sdpa_headsm_kernel(
    const float* __restrict__ Q, const float* __restrict__ K,
    const float* __restrict__ V, const int* __restrict__ M,
    float* __restrict__ O)
{
    __shared__ __align__(16) __bf16 pbuf[N_][TQ][40];

    const int tid  = threadIdx.x;
    const int n    = tid >> 6;
    const int lane = tid & 63;
    const int lo   = lane & 31;
    const int hi   = lane >> 5;

    const int q0 = blockIdx.x * TQ;
    const int b  = blockIdx.y;
    const int kz = blockIdx.z;
    const int FITERS = S_ / TK / 4;

    bf16x8 qf[4];
    {
        const float* qrow = Q + (((size_t)b * S_ + (size_t)(q0 + lo)) * N_ + n) * D_;
        #pragma unroll
        for (int ks = 0; ks < 4; ++ks) {
            const float* p = qrow + ks * 16 + hi * 8;
            float4 a0 = *(const float4*)(p);
            float4 a1 = *(const float4*)(p + 4);
            bf16x8 f;
            f[0] = (__bf16)a0.x; f[1] = (__bf16)a0.y;
            f[2] = (__bf16)a0.z; f[3] = (__bf16)a0.w;
            f[4] = (__bf16)a1.x; f[5] = (__bf16)a1.y;
            f[6] = (__bf16)a1.z; f[7] = (__bf16)a1.w;
            qf[ks] = f;
        }
    }

    f32x16 o0 = {};
    f32x16 o1 = {};

    for (int it = 0; it < FITERS; ++it) {
        const int k0 = (kz * FITERS + it) * TK;

        f32x16 s = {};
        #pragma unroll
        for (int ks = 0; ks < 4; ++ks) {
            const float* krow = K + (((size_t)b * S_ + (size_t)(k0 + lo)) * N_ + n) * D_
                                  + ks * 16 + hi * 8;
            float4 a0 = *(const float4*)(krow);
            float4 a1 = *(const float4*)(krow + 4);
            bf16x8 f;
            f[0] = (__bf16)a0.x; f[1] = (__bf16)a0.y;
            f[2] = (__bf16)a0.z; f[3] = (__bf16)a0.w;
            f[4] = (__bf16)a1.x; f[5] = (__bf16)a1.y;
            f[6] = (__bf16)a1.z; f[7] = (__bf16)a1.w;
            s = __builtin_amdgcn_mfma_f32_32x32x16_bf16(qf[ks], f, s, 0, 0, 0);
        }

        bf16x8 vf[2][2];
        #pragma unroll
        for (int kstep = 0; kstep < 2; ++kstep) {
            #pragma unroll
            for (int dt = 0; dt < 2; ++dt) {
                bf16x8 f;
                #pragma unroll
                for (int j = 0; j < 8; ++j) {
                    const int key = k0 + kstep * 16 + hi * 8 + j;
                    f[j] = (__bf16)V[(((size_t)b * S_ + key) * N_ + n) * D_ + dt * 32 + lo];
                }
                vf[kstep][dt] = f;
            }
        }

        #pragma unroll
        for (int r = 0; r < 16; ++r) {
            const int row = (r & 3) + 8 * (r >> 2) + 4 * hi;
            pbuf[n][row][lo] = (__bf16)__builtin_amdgcn_exp2f(s[r] * QSCALE);
        }

        __syncthreads();

        {
            const int tq = tid >> 5;
            const int tk = tid & 31;
            const int m = M[(size_t)b * S_ * S_ + (size_t)(q0 + tq) * S_ + (k0 + tk)];
            float pv[16];
            float sum = 0.f;
            #pragma unroll
            for (int j = 0; j < 16; ++j) { pv[j] = (float)pbuf[j][tq][tk]; sum += pv[j]; }
            const float rd = m ? (1.0f / sum) : __builtin_nanf("");
            #pragma unroll
            for (int j = 0; j < 16; ++j) pbuf[j][tq][tk] = (__bf16)(pv[j] * rd);
        }

        __syncthreads();

        #pragma unroll
        for (int kstep = 0; kstep < 2; ++kstep) {
            bf16x8 wf = *(const bf16x8*)&pbuf[n][lo][kstep * 16 + hi * 8];
            o0 = __builtin_amdgcn_mfma_f32_32x32x16_bf16(wf, vf[kstep][0], o0, 0, 0, 0);
            o1 = __builtin_amdgcn_mfma_f32_32x32x16_bf16(wf, vf[kstep][1], o1, 0, 0, 0);
        }

        __syncthreads();
    }

    #pragma unroll
    for (int r = 0; r < 16; ++r) {
        const int row = (r & 3) + 8 * (r >> 2) + 4 * hi;
        const size_t base = (((size_t)b * N_ + n) * S_ + (q0 + row)) * (size_t)D_;
        atomicAdd(&O[base + lo],      o0[r]);
        atomicAdd(&O[base + 32 + lo], o1[r]);
    }
}

extern "C" void kernel_launch(void* const* d_in, const int* in_sizes, int n_in,
                              void* d_out, int out_size, void* d_ws, size_t ws_size,
                              hipStream_t stream) {
    const float* Q = (const float*)d_in[0];
    const float* K = (const float*)d_in[1];
    const float* V = (const float*)d_in[2];
    const int*   M = (const int*)d_in[3];
    float* O = (float*)d_out;

    const size_t per  = (size_t)B_ * N_ * NT * 2048;       // 4,194,304 elements
    const size_t zcnt = (size_t)B_ * NT * NT * 1024;       // 8,388,608 elements
    const size_t need = (3 * per + zcnt) * sizeof(__bf16); // 42 MB

    if (ws_size >= need) {
        __bf16* QP = (__bf16*)d_ws;
        __bf16* KP = QP + per;
        __bf16* VP = KP + per;
        __bf16* Zrb = VP + per;
        cvt_qk_pack_kernel<<<dim3(NT, N_, B_ * 2), dim3(256), 0, stream>>>(Q, K, QP, KP);
        cvt_v_pack_kernel<<<dim3(S_ / 64, N_, B_), dim3(256), 0, stream>>>(V, VP);
        pass1_z_kernel<<<dim3(NT / 8, NT / 2, B_), dim3(256), 0, stream>>>(QP, KP, M, Zrb);
        pass2_av_kernel<<<dim3(N_, NT / 2, B_), dim3(256), 0, stream>>>(QP, KP, VP, Zrb, O);
    } else {
        hipMemsetAsync(d_out, 0, (size_t)out_size * sizeof(float), stream);
        sdpa_headsm_kernel<<<dim3(S_ / TQ, B_, 4), dim3(1024), 0, stream>>>(Q, K, V, M, O);
    }
}

// Round 7
// 216.120 us; speedup vs baseline: 1.1057x; 1.1057x over previous
//
#include <hip/hip_runtime.h>
#include <hip/hip_bf16.h>

// Head-axis-softmax SDPA, B=2 S=2048 N=16 D=64, fp32 in/out.
// softmax over HEADS (n) -> local per (b,q,k).
//
// R11: revert pass2 to R9's 1-qt / k-split-4 shape (70us, 56 VGPR, occ 40%,
// 0 LDS conflicts). R10's q-pair blocking cost a resident block (occ 23%)
// and reintroduced combine bank conflicts -> regression. Kept from R10:
//   - Zr in bf16 packed-fragment layout (zr = 2x b128 per tile, pass1
//     writes halve)
//   - head-major pass2 grid (n,qt,b): linear%8=n%8 -> each XCD's L2 holds
//     2 heads x 2 batches = 2MB hot K/V (<4MB)
//   - pass1 2ktx2qt blocking (R10's non-pass2 residual was faster).

#define B_ 2
#define S_ 2048
#define N_ 16
#define D_ 64
#define TQ 32
#define TK 32
#define NT 64   // S_/32 tiles per head

typedef __bf16 bf16x4 __attribute__((ext_vector_type(4)));
typedef __bf16 bf16x8 __attribute__((ext_vector_type(8)));
typedef float  f32x16 __attribute__((ext_vector_type(16)));
typedef unsigned int uint32x4 __attribute__((ext_vector_type(4)));

// scale folded into Q at conversion: 1/sqrt(64) * log2(e)
#define QSCALE 0.18033688011112042f

static __device__ __forceinline__ unsigned int cvt_pk_bf16(float a, float b) {
    // dst low16 = bf16(a), high16 = bf16(b)
    unsigned int r;
    asm("v_cvt_pk_bf16_f32 %0, %1, %2" : "=v"(r) : "v"(a), "v"(b));
    return r;
}
static __device__ __forceinline__ void permlane_swap(unsigned int& a, unsigned int& b) {
    // exchanges a's lanes[32:63] with b's lanes[0:31]
    asm("v_permlane32_swap_b32 %0, %1" : "+v"(a), "+v"(b));
}

// ---------------------------------------------------------------------------
// Pre-pass 1: Q,K [b,s,n,d] f32 -> fragment-major packed bf16.
// QP,KP[b][n][s-tile][ks][lane][8]; Q pre-scaled by QSCALE.
// ---------------------------------------------------------------------------
__global__ __launch_bounds__(256) void cvt_qk_pack_kernel(
    const float* __restrict__ Qf, const float* __restrict__ Kf,
    __bf16* __restrict__ QP, __bf16* __restrict__ KP)
{
    const int z = blockIdx.z;                  // 0..2B-1: first B -> Q, rest -> K
    const float* src = (z < B_) ? Qf : Kf;
    __bf16*      dst = (z < B_) ? QP : KP;
    const float scale = (z < B_) ? QSCALE : 1.0f;
    const int b  = (z < B_) ? z : z - B_;
    const int n  = blockIdx.y;
    const int st = blockIdx.x;                 // s-tile 0..63
    const int t  = threadIdx.x;
    const int ks   = t >> 6;
    const int lane = t & 63;
    const int lo   = lane & 31;
    const int hi   = lane >> 5;

    const float* p = &src[(((size_t)b * S_ + st * 32 + lo) * N_ + n) * D_ + ks * 16 + hi * 8];
    const float4 a0 = *(const float4*)p;
    const float4 a1 = *(const float4*)(p + 4);
    bf16x8 o;
    o[0] = (__bf16)(a0.x * scale); o[1] = (__bf16)(a0.y * scale);
    o[2] = (__bf16)(a0.z * scale); o[3] = (__bf16)(a0.w * scale);
    o[4] = (__bf16)(a1.x * scale); o[5] = (__bf16)(a1.y * scale);
    o[6] = (__bf16)(a1.z * scale); o[7] = (__bf16)(a1.w * scale);
    *(bf16x8*)&dst[(((size_t)b * N_ + n) * NT + st) * 2048 + (size_t)t * 8] = o;
}

// ---------------------------------------------------------------------------
// Pre-pass 2: V [b,s,n,d] f32 -> fragment-major packed bf16 (via LDS tile).
// VP[b][n][k-tile][kstep][dt][lane][8].
// ---------------------------------------------------------------------------
__global__ __launch_bounds__(256) void cvt_v_pack_kernel(
    const float* __restrict__ V, __bf16* __restrict__ VP)
{
    __shared__ __bf16 tile[64][68];  // +4 pad breaks bank aliasing
    const int s0 = blockIdx.x * 64;
    const int n  = blockIdx.y;
    const int b  = blockIdx.z;
    const int t  = threadIdx.x;

    {
        const int d4 = (t & 15) * 4;
        const int sr = t >> 4;
        #pragma unroll
        for (int r = 0; r < 4; ++r) {
            const int s = sr + r * 16;
            const float4 v = *(const float4*)&V[(((size_t)b * S_ + s0 + s) * N_ + n) * D_ + d4];
            tile[s][d4 + 0] = (__bf16)v.x;
            tile[s][d4 + 1] = (__bf16)v.y;
            tile[s][d4 + 2] = (__bf16)v.z;
            tile[s][d4 + 3] = (__bf16)v.w;
        }
    }
    __syncthreads();
    {
        const int kstep = t >> 7;        // 0..1
        const int dt    = (t >> 6) & 1;
        const int lane  = t & 63;
        const int lo    = lane & 31;
        const int hi    = lane >> 5;
        #pragma unroll
        for (int kt_sub = 0; kt_sub < 2; ++kt_sub) {
            bf16x8 o;
            #pragma unroll
            for (int j = 0; j < 8; ++j)
                o[j] = tile[kt_sub * 32 + kstep * 16 + hi * 8 + j][dt * 32 + lo];
            const size_t kt = (size_t)(blockIdx.x * 2 + kt_sub);
            *(bf16x8*)&VP[(((size_t)b * N_ + n) * NT + kt) * 2048 + (size_t)t * 8] = o;
        }
    }
}

// ---------------------------------------------------------------------------
// Pass 1: Zrb packed bf16 = mask ? 1/sum_n exp2(s_n) : NaN, in pass2's
// fragment layout: Zrb[((b*NT+kt)*NT+qt)*1024 + g*512 + lane*8 + j] holds
// Z^-1 at (q = qt*32+(lane&31), k = kt*32 + kap(g*8+j, lane>>5)),
// kap(r,hi) = (r&3)+8*(r>>2)+4*hi.
// Block = 4 waves; wave wv: k-tiles ktA=(bx*4+wv)*2, ktA+1;
// q-tiles qt0=by*2, qt0+1. SWAPPED QK^T (mfma(K,Q)): C-layout == packed order.
// 2x2 blocking: per head 16 frag loads -> 16 MFMA.
// ---------------------------------------------------------------------------
__global__ __launch_bounds__(256, 2) void pass1_z_kernel(
    const __bf16* __restrict__ QP, const __bf16* __restrict__ KP,
    const int* __restrict__ M, __bf16* __restrict__ Zrb)
{
    const int tid  = threadIdx.x;
    const int wv   = tid >> 6;
    const int lane = tid & 63;
    const int lo   = lane & 31;
    const int hi   = lane >> 5;

    const int ktA = (blockIdx.x * 4 + wv) * 2;
    const int qt0 = blockIdx.y * 2;
    const int b   = blockIdx.z;
    const int k0A = ktA * TK;
    const int q0  = qt0 * TQ;

    const __bf16* Qp = QP + ((size_t)b * N_ * NT + qt0) * 2048 + (size_t)lane * 8;
    const __bf16* Kp = KP + ((size_t)b * N_ * NT + ktA) * 2048 + (size_t)lane * 8;

    f32x16 zAA = {}, zAB = {}, zBA = {}, zBB = {};   // z[kt][qt]
    for (int h = 0; h < N_; ++h) {
        const __bf16* Qh = Qp + (size_t)h * NT * 2048;
        const __bf16* Kh = Kp + (size_t)h * NT * 2048;
        bf16x8 q0f[4], q1f[4], ka[4], kb[4];
        #pragma unroll
        for (int ks = 0; ks < 4; ++ks) {
            q0f[ks] = *(const bf16x8*)(Qh + ks * 512);
            q1f[ks] = *(const bf16x8*)(Qh + 2048 + ks * 512);
            ka[ks]  = *(const bf16x8*)(Kh + ks * 512);
            kb[ks]  = *(const bf16x8*)(Kh + 2048 + ks * 512);
        }
        f32x16 s;
        s = (f32x16){};
        #pragma unroll
        for (int ks = 0; ks < 4; ++ks) s = __builtin_amdgcn_mfma_f32_32x32x16_bf16(ka[ks], q0f[ks], s, 0, 0, 0);
        #pragma unroll
        for (int r = 0; r < 16; ++r) zAA[r] += __builtin_amdgcn_exp2f(s[r]);
        s = (f32x16){};
        #pragma unroll
        for (int ks = 0; ks < 4; ++ks) s = __builtin_amdgcn_mfma_f32_32x32x16_bf16(ka[ks], q1f[ks], s, 0, 0, 0);
        #pragma unroll
        for (int r = 0; r < 16; ++r) zAB[r] += __builtin_amdgcn_exp2f(s[r]);
        s = (f32x16){};
        #pragma unroll
        for (int ks = 0; ks < 4; ++ks) s = __builtin_amdgcn_mfma_f32_32x32x16_bf16(kb[ks], q0f[ks], s, 0, 0, 0);
        #pragma unroll
        for (int r = 0; r < 16; ++r) zBA[r] += __builtin_amdgcn_exp2f(s[r]);
        s = (f32x16){};
        #pragma unroll
        for (int ks = 0; ks < 4; ++ks) s = __builtin_amdgcn_mfma_f32_32x32x16_bf16(kb[ks], q1f[ks], s, 0, 0, 0);
        #pragma unroll
        for (int r = 0; r < 16; ++r) zBB[r] += __builtin_amdgcn_exp2f(s[r]);
    }

    // mask fast-path: AND-reduce rows q0..q0+63 x cols k0A..k0A+63 (int4).
    const size_t mb = (size_t)b * S_ * S_;
    int ok = 1;
    #pragma unroll
    for (int r = 0; r < 16; ++r) {
        const int4 mm = *(const int4*)&M[mb + (size_t)(q0 + 4 * r + (lane >> 4)) * S_
                                         + k0A + (lane & 15) * 4];
        ok &= (mm.x != 0) & (mm.y != 0) & (mm.z != 0) & (mm.w != 0);
    }

    float vAA[16], vAB[16], vBA[16], vBB[16];
    #pragma unroll
    for (int r = 0; r < 16; ++r) {
        vAA[r] = __builtin_amdgcn_rcpf(zAA[r]);
        vAB[r] = __builtin_amdgcn_rcpf(zAB[r]);
        vBA[r] = __builtin_amdgcn_rcpf(zBA[r]);
        vBB[r] = __builtin_amdgcn_rcpf(zBB[r]);
    }

    if (!__all(ok)) {
        // rare slow path: per-element mask (scattered; correctness only).
        // mask==0: ref softmax over all-(-inf) heads -> NaN weights.
        #pragma unroll
        for (int r = 0; r < 16; ++r) {
            const int kap = (r & 3) + 8 * (r >> 2) + 4 * hi;
            const size_t rowA = mb + (size_t)(q0 + lo) * S_;
            const size_t rowB = mb + (size_t)(q0 + 32 + lo) * S_;
            if (M[rowA + k0A + kap] == 0)      vAA[r] = __builtin_nanf("");
            if (M[rowB + k0A + kap] == 0)      vAB[r] = __builtin_nanf("");
            if (M[rowA + k0A + 32 + kap] == 0) vBA[r] = __builtin_nanf("");
            if (M[rowB + k0A + 32 + kap] == 0) vBB[r] = __builtin_nanf("");
        }
    }

    auto store_tile = [&](const float (&v)[16], int kt_, int qt_) {
        __bf16* Zt = Zrb + (((size_t)b * NT + kt_) * NT + qt_) * 1024 + (size_t)lane * 8;
        #pragma unroll
        for (int g = 0; g < 2; ++g) {
            uint32x4 u;
            #pragma unroll
            for (int i = 0; i < 4; ++i)
                u[i] = cvt_pk_bf16(v[g * 8 + 2 * i], v[g * 8 + 2 * i + 1]);
            *(bf16x8*)(Zt + g * 512) = __builtin_bit_cast(bf16x8, u);
        }
    };
    store_tile(vAA, ktA,     qt0);
    store_tile(vAB, ktA,     qt0 + 1);
    store_tile(vBA, ktA + 1, qt0);
    store_tile(vBB, ktA + 1, qt0 + 1);
}

// ---------------------------------------------------------------------------
// Pass 2: out[b,n,q,:] = sum_k (exp2(s)*zr) V[k,:].  (R9 shape)
// Block = 256 thr = 4 waves, ONE (q-tile, head, b) per block; wave w sweeps
// k-tiles [w*16, w*16+16). Swapped QK^T; cvt_pk+permlane PV A-frags;
// zr = 2x b128 bf16 packed loads. Grid (n, qt, b): linear%8 = n%8 -> each
// head's K/V plane XCD-L2-resident. End: chunked 2x16-row combine (16KB).
// ---------------------------------------------------------------------------
__global__ __launch_bounds__(256, 4) void pass2_av_kernel(
    const __bf16* __restrict__ QP, const __bf16* __restrict__ KP,
    const __bf16* __restrict__ VP, const __bf16* __restrict__ Zrb,
    float* __restrict__ O)
{
    __shared__ __align__(16) float obuf[4][16 * D_];    // 16 KB, end combine

    const int tid  = threadIdx.x;
    const int wv   = tid >> 6;
    const int lane = tid & 63;
    const int lo   = lane & 31;
    const int hi   = lane >> 5;

    const int n  = blockIdx.x;
    const int qt = blockIdx.y;
    const int b  = blockIdx.z;
    const int q0 = qt * TQ;

    const __bf16* Qh = QP + (((size_t)b * N_ + n) * NT + qt) * 2048 + (size_t)lane * 8;
    const __bf16* Kh = KP + (((size_t)b * N_ + n) * NT) * 2048 + (size_t)lane * 8;
    const __bf16* Vh = VP + (((size_t)b * N_ + n) * NT) * 2048 + (size_t)lane * 8;
    const __bf16* Zb = Zrb + (size_t)b * NT * NT * 1024 + (size_t)lane * 8;

    // Q fragments (pre-scaled). B-operand of the swapped QK^T.
    bf16x8 qf[4];
    #pragma unroll
    for (int ks = 0; ks < 4; ++ks)
        qf[ks] = *(const bf16x8*)(Qh + ks * 512);

    f32x16 o0 = {};  // out cols d =  0..31 (C layout)
    f32x16 o1 = {};  // out cols d = 32..63

    #pragma unroll 2
    for (int t = 0; t < 16; ++t) {
        const int kt = wv * 16 + t;
        const __bf16* Kt = Kh + (size_t)kt * 2048;
        const __bf16* Vt = Vh + (size_t)kt * 2048;
        const __bf16* Zt = Zb + ((size_t)kt * NT + qt) * 1024;

        // zr (bf16 packed): 2 b128 loads; za covers r=0..7, zb r=8..15.
        const bf16x8 za = *(const bf16x8*)(Zt);
        const bf16x8 zb = *(const bf16x8*)(Zt + 512);

        // K/V frags: lane-contiguous 1KB each.
        bf16x8 kf[4];
        #pragma unroll
        for (int ks = 0; ks < 4; ++ks) kf[ks] = *(const bf16x8*)(Kt + ks * 512);
        bf16x8 vf[2][2];
        #pragma unroll
        for (int kstep = 0; kstep < 2; ++kstep)
            #pragma unroll
            for (int dt = 0; dt < 2; ++dt)
                vf[kstep][dt] = *(const bf16x8*)(Vt + (kstep * 2 + dt) * 512);

        // swapped QK^T: S^T[key=row][q=lo]; lane (lo,hi) holds scores of
        // q = q0+lo at keys kap(r,hi) = (r&3)+8*(r>>2)+4*hi (+kt*32)
        f32x16 s = {};
        #pragma unroll
        for (int ks = 0; ks < 4; ++ks)
            s = __builtin_amdgcn_mfma_f32_32x32x16_bf16(kf[ks], qf[ks], s, 0, 0, 0);

        // w = exp2(s) * zr  (single v_exp_f32; NaN propagates for mask==0)
        float w[16];
        #pragma unroll
        for (int r = 0; r < 8; ++r)  w[r] = __builtin_amdgcn_exp2f(s[r]) * (float)za[r];
        #pragma unroll
        for (int r = 8; r < 16; ++r) w[r] = __builtin_amdgcn_exp2f(s[r]) * (float)zb[r - 8];

        // pack to bf16 + cross-half redistribute -> exact PV A-fragments.
        #pragma unroll
        for (int kstep = 0; kstep < 2; ++kstep) {
            const int e = kstep * 8;
            unsigned int d0 = cvt_pk_bf16(w[e + 0], w[e + 1]);
            unsigned int d1 = cvt_pk_bf16(w[e + 2], w[e + 3]);
            unsigned int d2 = cvt_pk_bf16(w[e + 4], w[e + 5]);
            unsigned int d3 = cvt_pk_bf16(w[e + 6], w[e + 7]);
            permlane_swap(d0, d2);
            permlane_swap(d1, d3);
            uint32x4 u; u[0] = d0; u[1] = d1; u[2] = d2; u[3] = d3;
            const bf16x8 pa = __builtin_bit_cast(bf16x8, u);
            o0 = __builtin_amdgcn_mfma_f32_32x32x16_bf16(pa, vf[kstep][0], o0, 0, 0, 0);
            o1 = __builtin_amdgcn_mfma_f32_32x32x16_bf16(pa, vf[kstep][1], o1, 0, 0, 0);
        }
    }

    // k-split combine, chunked 2 x 16 rows (obuf 16KB, e0=tid*4: 0 conflicts).
    #pragma unroll
    for (int half = 0; half < 2; ++half) {
        if (half) __syncthreads();   // protect obuf reuse
        #pragma unroll
        for (int r8 = 0; r8 < 8; ++r8) {
            const int r  = half * 8 + r8;
            const int lr = (r8 & 3) + 8 * (r8 >> 2) + 4 * hi;  // row - 16*half
            obuf[wv][lr * D_ + lo]      = o0[r];
            obuf[wv][lr * D_ + 32 + lo] = o1[r];
        }
        __syncthreads();
        const int e0 = tid * 4;          // 1024 f32 per half / 256 thr
        float a0 = 0.f, a1 = 0.f, a2 = 0.f, a3 = 0.f;
        #pragma unroll
        for (int w = 0; w < 4; ++w) {
            const float4 x = *(const float4*)&obuf[w][e0];
            a0 += x.x; a1 += x.y; a2 += x.z; a3 += x.w;
        }
        const int q = half * 16 + (e0 >> 6);
        const int d = e0 & 63;
        *(float4*)&O[(((size_t)b * N_ + n) * S_ + q0 + q) * (size_t)D_ + d]
            = make_float4(a0, a1, a2, a3);
    }
}

// ---------------------------------------------------------------------------
// Fallback (fp32 inputs): used only if ws is too small.
// ---------------------------------------------------------------------------
__global__ __launch_bounds__(1024) void sdpa_headsm_kernel(
    const float* __restrict__ Q, const float* __restrict__ K,
    const float* __restrict__ V, const int* __restrict__ M,
    float* __restrict__ O)
{
    __shared__ __align__(16) __bf16 pbuf[N_][TQ][40];

    const int tid  = threadIdx.x;
    const int n    = tid >> 6;
    const int lane = tid & 63;
    const int lo   = lane & 31;
    const int hi   = lane >> 5;

    const int q0 = blockIdx.x * TQ;
    const int b  = blockIdx.y;
    const int kz = blockIdx.z;
    const int FITERS = S_ / TK / 4;

    bf16x8 qf[4];
    {
        const float* qrow = Q + (((size_t)b * S_ + (size_t)(q0 + lo)) * N_ + n) * D_;
        #pragma unroll
        for (int ks = 0; ks < 4; ++ks) {
            const float* p = qrow + ks * 16 + hi * 8;
            float4 a0 = *(const float4*)(p);
            float4 a1 = *(const float4*)(p + 4);
            bf16x8 f;
            f[0] = (__bf16)a0.x; f[1] = (__bf16)a0.y;
            f[2] = (__bf16)a0.z; f[3] = (__bf16)a0.w;
            f[4] = (__bf16)a1.x; f[5] = (__bf16)a1.y;
            f[6] = (__bf16)a1.z; f[7] = (__bf16)a1.w;
            qf[ks] = f;
        }
    }

    f32x16 o0 = {};
    f32x16 o1 = {};

    for (int it = 0; it < FITERS; ++it) {
        const int k0 = (kz * FITERS + it) * TK;

        f32x16 s = {};
        #pragma unroll
        for (int ks = 0; ks < 4; ++ks) {
            const float* krow = K + (((size_t)b * S_ + (size_t)(k0 + lo)) * N_ + n) * D_
                                  + ks * 16 + hi * 8;
            float4 a0 = *(const float4*)(krow);
            float4 a1 = *(const float4*)(krow + 4);
            bf16x8 f;
            f[0] = (__bf16)a0.x; f[1] = (__bf16)a0.y;
            f[2] = (__bf16)a0.z; f[3] = (__bf16)a0.w;
            f[4] = (__bf16)a1.x; f[5] = (__bf16)a1.y;
            f[6] = (__bf16)a1.z; f[7] = (__bf16)a1.w;
            s = __builtin_amdgcn_mfma_f32_32x32x16_bf16(qf[ks], f, s, 0, 0, 0);
        }

        bf16x8 vf[2][2];
        #pragma unroll
        for (int kstep = 0; kstep < 2; ++kstep) {
            #pragma unroll
            for (int dt = 0; dt < 2; ++dt) {
                bf16x8 f;
                #pragma unroll
                for (int j = 0; j < 8; ++j) {
                    const int key = k0 + kstep * 16 + hi * 8 + j;
                    f[j] = (__bf16)V[(((size_t)b * S_ + key) * N_ + n) * D_ + dt * 32 + lo];
                }
                vf[kstep][dt] = f;
            }
        }

        #pragma unroll
        for (int r = 0; r < 16; ++r) {
            const int row = (r & 3) + 8 * (r >> 2) + 4 * hi;
            pbuf[n][row][lo] = (__bf16)__builtin_amdgcn_exp2f(s[r] * QSCALE);
        }

        __syncthreads();

        {
            const int tq = tid >> 5;
            const int tk = tid & 31;
            const int m = M[(size_t)b * S_ * S_ + (size_t)(q0 + tq) * S_ + (k0 + tk)];
            float pv[16];
            float sum = 0.f;
            #pragma unroll
            for (int j = 0; j < 16; ++j) { pv[j] = (float)pbuf[j][tq][tk]; sum += pv[j]; }
            const float rd = m ? (1.0f / sum) : __builtin_nanf("");
            #pragma unroll
            for (int j = 0; j < 16; ++j) pbuf[j][tq][tk] = (__bf16)(pv[j] * rd);
        }

        __syncthreads();

        #pragma unroll
        for (int kstep = 0; kstep < 2; ++kstep) {
            bf16x8 wf = *(const bf16x8*)&pbuf[n][lo][kstep * 16 + hi * 8];
            o0 = __builtin_amdgcn_mfma_f32_32x32x16_bf16(wf, vf[kstep][0], o0, 0, 0, 0);
            o1 = __builtin_amdgcn_mfma_f32_32x32x16_bf16(wf, vf[kstep][1], o1, 0, 0, 0);
        }

        __syncthreads();
    }

    #pragma unroll
    for (int r = 0; r < 16; ++r) {
        const int row = (r & 3) + 8 * (r >> 2) + 4 * hi;
        const size_t base = (((size_t)b * N_ + n) * S_ + (q0 + row)) * (size_t)D_;
        atomicAdd(&O[base + lo],      o0[r]);
        atomicAdd(&O[base + 32 + lo], o1[r]);
    }
}

extern "C" void kernel_launch(void* const* d_in, const int* in_sizes, int n_in,
                              void* d_out, int out_size, void* d_ws, size_t ws_size,
                              hipStream_t stream) {
    const float* Q = (const float*)d_in[0];
    const float* K = (const float*)d_in[1];
    const float* V = (const float*)d_in[2];
    const int*   M = (const int*)d_in[3];
    float* O = (float*)d_out;

    const size_t per  = (size_t)B_ * N_ * NT * 2048;       // 4,194,304 elements
    const size_t zcnt = (size_t)B_ * NT * NT * 1024;       // 8,388,608 elements
    const size_t need = (3 * per + zcnt) * sizeof(__bf16); // 42 MB

    if (ws_size >= need) {
        __bf16* QP = (__bf16*)d_ws;
        __bf16* KP = QP + per;
        __bf16* VP = KP + per;
        __bf16* Zrb = VP + per;
        cvt_qk_pack_kernel<<<dim3(NT, N_, B_ * 2), dim3(256), 0, stream>>>(Q, K, QP, KP);
        cvt_v_pack_kernel<<<dim3(S_ / 64, N_, B_), dim3(256), 0, stream>>>(V, VP);
        pass1_z_kernel<<<dim3(NT / 8, NT / 2, B_), dim3(256), 0, stream>>>(QP, KP, M, Zrb);
        pass2_av_kernel<<<dim3(N_, NT, B_), dim3(256), 0, stream>>>(QP, KP, VP, Zrb, O);
    } else {
        hipMemsetAsync(d_out, 0, (size_t)out_size * sizeof(float), stream);
        sdpa_headsm_kernel<<<dim3(S_ / TQ, B_, 4), dim3(1024), 0, stream>>>(Q, K, V, M, O);
    }
}